// Round 1
// baseline (1223.635 us; speedup 1.0000x reference)
//
#include <hip/hip_runtime.h>
#include <hip/hip_bf16.h>

#define W_BIT 4
#define OUT_F 11008
#define IN_F 4096
#define KRANK 16
#define M_DIM 8192
#define QW_PLANE (OUT_F * IN_F / 8)

#define BM 128
#define BN 128
#define BK 64
#define N_DIM OUT_F
#define K_DIM IN_F

typedef __attribute__((ext_vector_type(8))) short short8;
typedef __attribute__((ext_vector_type(4))) float f32x4;

// round-to-nearest-even fp32 -> bf16 (NaN not expected in this workload)
__device__ __forceinline__ short f2bf(float f) {
    union { float f; unsigned u; } v;
    v.f = f;
    unsigned r = v.u + 0x7fffu + ((v.u >> 16) & 1u);
    return (short)(r >> 16);
}

// async global->LDS, 16B per lane (global_load_lds_dwordx4)
__device__ __forceinline__ void async16(void* lds, const void* g) {
    __builtin_amdgcn_global_load_lds(
        (const __attribute__((address_space(1))) unsigned int*)g,
        (__attribute__((address_space(3))) unsigned int*)lds,
        16, 0, 0);
}

// ---------------------------------------------------------------------------
// Kernel 1: x fp32 -> bf16
// ---------------------------------------------------------------------------
__global__ __launch_bounds__(256) void convert_x_kernel(
    const float* __restrict__ x, short* __restrict__ xb) {
    int tid = blockIdx.x * blockDim.x + threadIdx.x;
    int stride = gridDim.x * blockDim.x;
    const int n8 = (M_DIM * IN_F) / 8;
    for (int i = tid; i < n8; i += stride) {
        f32x4 a = ((const f32x4*)x)[2 * i];
        f32x4 b = ((const f32x4*)x)[2 * i + 1];
        short8 o;
        o[0] = f2bf(a[0]); o[1] = f2bf(a[1]); o[2] = f2bf(a[2]); o[3] = f2bf(a[3]);
        o[4] = f2bf(b[0]); o[5] = f2bf(b[1]); o[6] = f2bf(b[2]); o[7] = f2bf(b[3]);
        ((short8*)xb)[i] = o;
    }
}

// ---------------------------------------------------------------------------
// Kernel 2: reconstruct w[o][in] = sum_i sign_i(o,in) * (u_i[o,:] . vt_i[:,in])
// block: 256 threads, tile 64 o-rows x 128 in-cols; per-thread 4x8 micro-tile
// ---------------------------------------------------------------------------
__global__ __launch_bounds__(256) void reconstruct_w_kernel(
    const int* __restrict__ qw, const float* __restrict__ u,
    const float* __restrict__ vt, short* __restrict__ wb) {
    __shared__ float vts[W_BIT][KRANK][128];  // 32 KB, [i][k][c]
    __shared__ float us[W_BIT][KRANK][64];    // 16 KB, [i][k][o] (k-major for float4 reads)

    const int t = threadIdx.x;
    const int o0 = blockIdx.y * 64;
    const int c0 = blockIdx.x * 128;

    // stage vt tile (coalesced: c fastest)
    for (int idx = t; idx < W_BIT * KRANK * 128; idx += 256) {
        int i = idx >> 11;
        int rem = idx & 2047;
        int k = rem >> 7;
        int c = rem & 127;
        vts[i][k][c] = vt[(i * KRANK + k) * IN_F + c0 + c];
    }
    // stage u tile transposed
    for (int idx = t; idx < W_BIT * KRANK * 64; idx += 256) {
        int i = idx >> 10;
        int rem = idx & 1023;
        int o = rem >> 4;
        int k = rem & 15;
        us[i][k][o] = u[((size_t)i * OUT_F + o0 + o) * KRANK + k];
    }
    __syncthreads();

    const int to = (t >> 4) * 4;   // 0..60
    const int tc = (t & 15) * 8;   // 0..120

    float wacc[4][8];
#pragma unroll
    for (int r = 0; r < 4; ++r)
#pragma unroll
        for (int c = 0; c < 8; ++c) wacc[r][c] = 0.f;

#pragma unroll
    for (int i = 0; i < W_BIT; ++i) {
        float dot[4][8];
#pragma unroll
        for (int r = 0; r < 4; ++r)
#pragma unroll
            for (int c = 0; c < 8; ++c) dot[r][c] = 0.f;

#pragma unroll
        for (int k = 0; k < KRANK; ++k) {
            f32x4 uv = *(const f32x4*)&us[i][k][to];
            f32x4 v0 = *(const f32x4*)&vts[i][k][tc];
            f32x4 v1 = *(const f32x4*)&vts[i][k][tc + 4];
#pragma unroll
            for (int r = 0; r < 4; ++r) {
#pragma unroll
                for (int c = 0; c < 4; ++c) {
                    dot[r][c]     += uv[r] * v0[c];
                    dot[r][c + 4] += uv[r] * v1[c];
                }
            }
        }
#pragma unroll
        for (int r = 0; r < 4; ++r) {
            unsigned byte = (unsigned)qw[i * QW_PLANE + (((o0 + to + r) * IN_F + c0 + tc) >> 3)];
#pragma unroll
            for (int c = 0; c < 8; ++c) {
                wacc[r][c] += ((byte >> c) & 1u) ? dot[r][c] : -dot[r][c];
            }
        }
    }

#pragma unroll
    for (int r = 0; r < 4; ++r) {
        short8 o8;
#pragma unroll
        for (int c = 0; c < 8; ++c) o8[c] = f2bf(wacc[r][c]);
        *(short8*)&wb[(size_t)(o0 + to + r) * IN_F + c0 + tc] = o8;
    }
}

// ---------------------------------------------------------------------------
// Kernel 3: C[M,N] = A[M,K] @ B[N,K]^T  (bf16 in, fp32 out)
// m97-structure: 128x128 tile, BK=64, 4 waves 2x2, global_load_lds width=16
// ---------------------------------------------------------------------------
__global__ __launch_bounds__(256) void gemm_bt_kernel(
    const short* __restrict__ A, const short* __restrict__ B, float* __restrict__ C) {
    __shared__ short As[BM * BK];  // 16 KB, row-major [128][64]
    __shared__ short Bs[BN * BK];  // 16 KB

    const int t = threadIdx.x;
    const int lane = t & 63;
    const int wid = t >> 6;
    const int nbn = N_DIM / BN;  // 86
    const int bid = blockIdx.x;
    // bijective XCD swizzle (grid = 5504, divisible by 8)
    const int cpx = gridDim.x >> 3;
    const int swz = (bid & 7) * cpx + (bid >> 3);
    const int bm = swz / nbn;
    const int bn = swz % nbn;
    const int row0 = bm * BM, col0 = bn * BN;
    const int wr = wid >> 1, wc = wid & 1;
    const int fr = lane & 15, fq = lane >> 4;

    f32x4 acc[4][4];
#pragma unroll
    for (int mm = 0; mm < 4; ++mm)
#pragma unroll
        for (int nn = 0; nn < 4; ++nn) acc[mm][nn] = (f32x4)0.f;

    // staging: issue i covers rows [i*32, i*32+32), each thread 16B
    const int srow = t >> 3;         // 0..31
    const int scol = (t & 7) * 8;    // bf16 elems
    const short* gA = A + (size_t)(row0 + srow) * K_DIM + scol;
    const short* gB = B + (size_t)(col0 + srow) * K_DIM + scol;
    short* lA = &As[t * 8];
    short* lB = &Bs[t * 8];

    for (int kt = 0; kt < K_DIM; kt += BK) {
#pragma unroll
        for (int i = 0; i < 4; ++i) {
            async16(lA + i * 2048, gA + (size_t)i * 32 * K_DIM + kt);
            async16(lB + i * 2048, gB + (size_t)i * 32 * K_DIM + kt);
        }
        __syncthreads();  // vmcnt(0) drain before barrier makes staged data visible
#pragma unroll
        for (int kk = 0; kk < BK; kk += 32) {
            short8 af[4], bfr[4];
#pragma unroll
            for (int mm = 0; mm < 4; ++mm)
                af[mm] = *(const short8*)&As[(wr * 64 + mm * 16 + fr) * BK + kk + fq * 8];
#pragma unroll
            for (int nn = 0; nn < 4; ++nn)
                bfr[nn] = *(const short8*)&Bs[(wc * 64 + nn * 16 + fr) * BK + kk + fq * 8];
#pragma unroll
            for (int mm = 0; mm < 4; ++mm)
#pragma unroll
                for (int nn = 0; nn < 4; ++nn)
                    acc[mm][nn] = __builtin_amdgcn_mfma_f32_16x16x32_bf16(
                        af[mm], bfr[nn], acc[mm][nn], 0, 0, 0);
        }
        __syncthreads();
    }

    // epilogue: C/D layout col = lane&15, row = (lane>>4)*4 + j
#pragma unroll
    for (int mm = 0; mm < 4; ++mm) {
#pragma unroll
        for (int nn = 0; nn < 4; ++nn) {
            f32x4 v = acc[mm][nn];
            int r0 = row0 + wr * 64 + mm * 16 + fq * 4;
            int cc = col0 + wc * 64 + nn * 16 + fr;
#pragma unroll
            for (int j = 0; j < 4; ++j)
                C[(size_t)(r0 + j) * N_DIM + cc] = v[j];
        }
    }
}

// ---------------------------------------------------------------------------
extern "C" void kernel_launch(void* const* d_in, const int* in_sizes, int n_in,
                              void* d_out, int out_size, void* d_ws, size_t ws_size,
                              hipStream_t stream) {
    const float* x  = (const float*)d_in[0];
    const int*   qw = (const int*)d_in[1];
    const float* u  = (const float*)d_in[2];
    const float* vt = (const float*)d_in[3];
    float* out = (float*)d_out;

    // workspace layout: wb bf16 [OUT_F][IN_F] (90,177,536 B) then xb bf16 [M][K] (67,108,864 B)
    const size_t wb_bytes = (size_t)OUT_F * IN_F * 2;
    short* wb = (short*)d_ws;
    short* xb = (short*)((char*)d_ws + wb_bytes);

    hipLaunchKernelGGL(convert_x_kernel, dim3(2048), dim3(256), 0, stream, x, xb);
    hipLaunchKernelGGL(reconstruct_w_kernel, dim3(IN_F / 128, OUT_F / 64), dim3(256), 0, stream,
                       qw, u, vt, wb);
    hipLaunchKernelGGL(gemm_bt_kernel, dim3((M_DIM / BM) * (N_DIM / BN)), dim3(256), 0, stream,
                       xb, wb, out);
}

// Round 2
// 915.920 us; speedup vs baseline: 1.3360x; 1.3360x over previous
//
#include <hip/hip_runtime.h>
#include <hip/hip_bf16.h>

#define W_BIT 4
#define OUT_F 11008
#define IN_F 4096
#define KRANK 16
#define M_DIM 8192
#define QW_PLANE (OUT_F * IN_F / 8)

#define N_DIM OUT_F
#define K_DIM IN_F
#define NT 64              // K tiles of 64
#define NBN 43             // N_DIM / 256

typedef __attribute__((ext_vector_type(8))) short short8;
typedef __attribute__((ext_vector_type(4))) float f32x4;

__device__ __forceinline__ short f2bf(float f) {
    union { float f; unsigned u; } v;
    v.f = f;
    unsigned r = v.u + 0x7fffu + ((v.u >> 16) & 1u);
    return (short)(r >> 16);
}

__device__ __forceinline__ void async16(void* lds, const void* g) {
    __builtin_amdgcn_global_load_lds(
        (const __attribute__((address_space(1))) unsigned int*)g,
        (__attribute__((address_space(3))) unsigned int*)lds,
        16, 0, 0);
}

#define BAR() __builtin_amdgcn_s_barrier()
#define LGKM0() do { asm volatile("s_waitcnt lgkmcnt(0)" ::: "memory"); \
                     __builtin_amdgcn_sched_barrier(0); } while (0)
#define VM8() asm volatile("s_waitcnt vmcnt(8)" ::: "memory")
#define VM0() asm volatile("s_waitcnt vmcnt(0)" ::: "memory")
#define PRIO1() __builtin_amdgcn_s_setprio(1)
#define PRIO0() __builtin_amdgcn_s_setprio(0)
#define SBAR0() __builtin_amdgcn_sched_barrier(0)

// ---------------------------------------------------------------------------
// Kernel 1: x fp32 -> bf16
// ---------------------------------------------------------------------------
__global__ __launch_bounds__(256) void convert_x_kernel(
    const float* __restrict__ x, short* __restrict__ xb) {
    int tid = blockIdx.x * blockDim.x + threadIdx.x;
    int stride = gridDim.x * blockDim.x;
    const int n8 = (M_DIM * IN_F) / 8;
    for (int i = tid; i < n8; i += stride) {
        f32x4 a = ((const f32x4*)x)[2 * i];
        f32x4 b = ((const f32x4*)x)[2 * i + 1];
        short8 o;
        o[0] = f2bf(a[0]); o[1] = f2bf(a[1]); o[2] = f2bf(a[2]); o[3] = f2bf(a[3]);
        o[4] = f2bf(b[0]); o[5] = f2bf(b[1]); o[6] = f2bf(b[2]); o[7] = f2bf(b[3]);
        ((short8*)xb)[i] = o;
    }
}

// ---------------------------------------------------------------------------
// Kernel 2: reconstruct w (unchanged from passing round)
// ---------------------------------------------------------------------------
__global__ __launch_bounds__(256) void reconstruct_w_kernel(
    const int* __restrict__ qw, const float* __restrict__ u,
    const float* __restrict__ vt, short* __restrict__ wb) {
    __shared__ float vts[W_BIT][KRANK][128];
    __shared__ float us[W_BIT][KRANK][64];

    const int t = threadIdx.x;
    const int o0 = blockIdx.y * 64;
    const int c0 = blockIdx.x * 128;

    for (int idx = t; idx < W_BIT * KRANK * 128; idx += 256) {
        int i = idx >> 11;
        int rem = idx & 2047;
        int k = rem >> 7;
        int c = rem & 127;
        vts[i][k][c] = vt[(i * KRANK + k) * IN_F + c0 + c];
    }
    for (int idx = t; idx < W_BIT * KRANK * 64; idx += 256) {
        int i = idx >> 10;
        int rem = idx & 1023;
        int o = rem >> 4;
        int k = rem & 15;
        us[i][k][o] = u[((size_t)i * OUT_F + o0 + o) * KRANK + k];
    }
    __syncthreads();

    const int to = (t >> 4) * 4;
    const int tc = (t & 15) * 8;

    float wacc[4][8];
#pragma unroll
    for (int r = 0; r < 4; ++r)
#pragma unroll
        for (int c = 0; c < 8; ++c) wacc[r][c] = 0.f;

#pragma unroll
    for (int i = 0; i < W_BIT; ++i) {
        float dot[4][8];
#pragma unroll
        for (int r = 0; r < 4; ++r)
#pragma unroll
            for (int c = 0; c < 8; ++c) dot[r][c] = 0.f;

#pragma unroll
        for (int k = 0; k < KRANK; ++k) {
            f32x4 uv = *(const f32x4*)&us[i][k][to];
            f32x4 v0 = *(const f32x4*)&vts[i][k][tc];
            f32x4 v1 = *(const f32x4*)&vts[i][k][tc + 4];
#pragma unroll
            for (int r = 0; r < 4; ++r) {
#pragma unroll
                for (int c = 0; c < 4; ++c) {
                    dot[r][c]     += uv[r] * v0[c];
                    dot[r][c + 4] += uv[r] * v1[c];
                }
            }
        }
#pragma unroll
        for (int r = 0; r < 4; ++r) {
            unsigned byte = (unsigned)qw[i * QW_PLANE + (((o0 + to + r) * IN_F + c0 + tc) >> 3)];
#pragma unroll
            for (int c = 0; c < 8; ++c) {
                wacc[r][c] += ((byte >> c) & 1u) ? dot[r][c] : -dot[r][c];
            }
        }
    }

#pragma unroll
    for (int r = 0; r < 4; ++r) {
        short8 o8;
#pragma unroll
        for (int c = 0; c < 8; ++c) o8[c] = f2bf(wacc[r][c]);
        *(short8*)&wb[(size_t)(o0 + to + r) * IN_F + c0 + tc] = o8;
    }
}

// ---------------------------------------------------------------------------
// Kernel 3: C[M,N] = A[M,K] @ B[N,K]^T, 256x256 tile, BK=64, 8 waves (2x4),
// 4-phase fine interleave, counted vmcnt(8), XOR-swizzled LDS (both-sides),
// register-double-buffered fragments.
// LDS (dynamic, 128 KiB as shorts): buf b: A at b*32768, B at b*32768+16384.
// ---------------------------------------------------------------------------
__global__ __launch_bounds__(512, 2) void gemm256_kernel(
    const short* __restrict__ A, const short* __restrict__ B, float* __restrict__ C) {
    extern __shared__ short lds[];

    const int t = threadIdx.x;
    const int lane = t & 63, wid = t >> 6;
    const int wr = wid >> 2, wc = wid & 3;       // 2 x 4 wave grid
    const int fr = lane & 15, fq = lane >> 4;

    const int bid = blockIdx.x;
    const int cpx = gridDim.x >> 3;              // 172 (grid 1376 % 8 == 0)
    const int swz = (bid & 7) * cpx + (bid >> 3);
    const int bm = swz / NBN, bn = swz % NBN;
    const long row0 = (long)bm * 256, col0 = (long)bn * 256;

    // ---- staging addresses (linear LDS dest, inverse-swizzled global source)
    const int srow_b = t >> 3;                                 // 0..63
    const int scol = (((t & 7) ^ ((t >> 3) & 7)) << 3);        // 16B-chunk swizzle
    const short* gA = A + (row0 + srow_b) * K_DIM + scol;
    const short* gB = B + (col0 + srow_b) * K_DIM + scol;
    const int ldst = t * 8;                                    // chunk l at +l*4096 shorts

    // ---- fragment read offsets (swizzled col)
    const int arow = (wr * 128 + fr) * 64;
    const int brow = (wc * 64 + fr) * 64;
    const int cswz = (fr & 7) << 3;
    const int colk0  = (fq << 3) ^ cswz;          // kk=0
    const int colk32 = (32 | (fq << 3)) ^ cswz;   // kk=32

    f32x4 acc[8][4];
#pragma unroll
    for (int m = 0; m < 8; ++m)
#pragma unroll
        for (int n = 0; n < 4; ++n) acc[m][n] = (f32x4)0.f;

    short8 af0[8], af1[8], bf0[4], bf1[4];

#define STAGE4(gp, base, ktcol)                                        \
    _Pragma("unroll") for (int l = 0; l < 4; ++l)                      \
        async16(&lds[(base) + ldst + l * 4096],                        \
                (gp) + (size_t)l * 64 * K_DIM + (ktcol))

#define LDA8(dst, base, colk)                                          \
    _Pragma("unroll") for (int m = 0; m < 8; ++m)                      \
        dst[m] = *(const short8*)&lds[(base) + arow + m * 1024 + (colk)]

#define LDB1(dst, n, base, colk)                                       \
    dst[n] = *(const short8*)&lds[(base) + 16384 + brow + (n) * 1024 + (colk)]

#define MF2(A8, B4, nlo)                                               \
    _Pragma("unroll") for (int m = 0; m < 8; ++m) {                    \
        acc[m][nlo] = __builtin_amdgcn_mfma_f32_16x16x32_bf16(         \
            A8[m], B4[nlo], acc[m][nlo], 0, 0, 0);                     \
        acc[m][(nlo) + 1] = __builtin_amdgcn_mfma_f32_16x16x32_bf16(   \
            A8[m], B4[(nlo) + 1], acc[m][(nlo) + 1], 0, 0, 0);         \
    }

    // ---- prologue: stage K0 -> buf0, K1 -> buf1 (16 loads/thread)
    STAGE4(gA, 0, 0);
    STAGE4(gB, 16384, 0);
    STAGE4(gA, 32768, 64);
    STAGE4(gB, 32768 + 16384, 64);
    VM8();          // K0 landed (K1's 8 loads may remain in flight)
    BAR();
    // P0: read K0 kk=0 fragments
    LDA8(af0, 0, colk0);
    LDB1(bf0, 0, 0, colk0); LDB1(bf0, 1, 0, colk0);
    LDB1(bf0, 2, 0, colk0); LDB1(bf0, 3, 0, colk0);

    for (int g = 0; g < NT; ++g) {
        const int ab  = (g & 1) * 32768;         // current buffer
        const int ab2 = ((g & 1) ^ 1) * 32768;   // other buffer (K-tile g+1)
        const bool st2 = (g + 2 < NT);
        const bool rd1 = (g + 1 < NT);
        const size_t kt2 = (size_t)(g + 2) * 64;

        // ---- P1: read A kk32 (8) + B kk32 n01 (2); MFMA kk0 x n01
        LDA8(af1, ab, colk32);
        LDB1(bf1, 0, ab, colk32);
        LDB1(bf1, 1, ab, colk32);
        BAR();
        LGKM0();
        PRIO1(); MF2(af0, bf0, 0); PRIO0();
        SBAR0();
        BAR();

        // ---- P2: stage A(g+2) into current buf (A region dead after P1);
        //          read B kk32 n23; MFMA kk0 x n23
        if (st2) STAGE4(gA, ab, kt2);
        LDB1(bf1, 2, ab, colk32);
        LDB1(bf1, 3, ab, colk32);
        BAR();
        LGKM0();
        PRIO1(); MF2(af0, bf0, 2); PRIO0();
        SBAR0();
        BAR();

        // ---- P3: stage B(g+2) (B region dead after P2); MFMA kk32 x n01;
        //          counted vmcnt: K-tile g+1 landed (only P2+P3 stages newer)
        if (st2) STAGE4(gB, ab + 16384, kt2);
        BAR();
        PRIO1(); MF2(af1, bf1, 0); PRIO0();
        if (st2) { VM8(); } else { VM0(); }
        SBAR0();
        BAR();

        // ---- P4: read next K-tile kk0 fragments (12); MFMA kk32 x n23
        if (rd1) {
            LDA8(af0, ab2, colk0);
            LDB1(bf0, 0, ab2, colk0); LDB1(bf0, 1, ab2, colk0);
            LDB1(bf0, 2, ab2, colk0); LDB1(bf0, 3, ab2, colk0);
        }
        BAR();
        LGKM0();
        PRIO1(); MF2(af1, bf1, 2); PRIO0();
        SBAR0();
        BAR();
    }

    // ---- epilogue: C/D layout col = lane&15, row = (lane>>4)*4 + j
#pragma unroll
    for (int m = 0; m < 8; ++m) {
#pragma unroll
        for (int n = 0; n < 4; ++n) {
            f32x4 v = acc[m][n];
            long r0 = row0 + wr * 128 + m * 16 + fq * 4;
            long cc = col0 + wc * 64 + n * 16 + fr;
#pragma unroll
            for (int jj = 0; jj < 4; ++jj)
                C[(size_t)(r0 + jj) * N_DIM + cc] = v[jj];
        }
    }
#undef STAGE4
#undef LDA8
#undef LDB1
#undef MF2
}

// ---------------------------------------------------------------------------
extern "C" void kernel_launch(void* const* d_in, const int* in_sizes, int n_in,
                              void* d_out, int out_size, void* d_ws, size_t ws_size,
                              hipStream_t stream) {
    const float* x  = (const float*)d_in[0];
    const int*   qw = (const int*)d_in[1];
    const float* u  = (const float*)d_in[2];
    const float* vt = (const float*)d_in[3];
    float* out = (float*)d_out;

    const size_t wb_bytes = (size_t)OUT_F * IN_F * 2;
    short* wb = (short*)d_ws;
    short* xb = (short*)((char*)d_ws + wb_bytes);

    // allow 128 KiB dynamic LDS (host-side attribute, capture-safe, idempotent)
    (void)hipFuncSetAttribute((const void*)gemm256_kernel,
                              hipFuncAttributeMaxDynamicSharedMemorySize, 131072);

    hipLaunchKernelGGL(convert_x_kernel, dim3(2048), dim3(256), 0, stream, x, xb);
    hipLaunchKernelGGL(reconstruct_w_kernel, dim3(IN_F / 128, OUT_F / 64), dim3(256), 0, stream,
                       qw, u, vt, wb);
    hipLaunchKernelGGL(gemm256_kernel, dim3((M_DIM / 256) * (N_DIM / 256)), dim3(512), 131072,
                       stream, xb, wb, out);
}

// Round 3
// 901.038 us; speedup vs baseline: 1.3580x; 1.0165x over previous
//
#include <hip/hip_runtime.h>
#include <hip/hip_bf16.h>

#define W_BIT 4
#define OUT_F 11008
#define IN_F 4096
#define KRANK 16
#define M_DIM 8192
#define QW_PLANE (OUT_F * IN_F / 8)

#define N_DIM OUT_F
#define K_DIM IN_F
#define NT 64              // K tiles of 64
#define NBN 43             // N_DIM / 256

typedef __attribute__((ext_vector_type(8))) short short8;
typedef __attribute__((ext_vector_type(4))) float f32x4;

__device__ __forceinline__ short f2bf(float f) {
    union { float f; unsigned u; } v;
    v.f = f;
    unsigned r = v.u + 0x7fffu + ((v.u >> 16) & 1u);
    return (short)(r >> 16);
}

__device__ __forceinline__ void async16(void* lds, const void* g) {
    __builtin_amdgcn_global_load_lds(
        (const __attribute__((address_space(1))) unsigned int*)g,
        (__attribute__((address_space(3))) unsigned int*)lds,
        16, 0, 0);
}

#define BAR() __builtin_amdgcn_s_barrier()
#define SBAR0() __builtin_amdgcn_sched_barrier(0)
#define LGKM(n) do { asm volatile("s_waitcnt lgkmcnt(" #n ")" ::: "memory"); \
                     __builtin_amdgcn_sched_barrier(0); } while (0)
#define VMC(n) do { asm volatile("s_waitcnt vmcnt(" #n ")" ::: "memory"); \
                    __builtin_amdgcn_sched_barrier(0); } while (0)
#define PRIO1() __builtin_amdgcn_s_setprio(1)
#define PRIO0() __builtin_amdgcn_s_setprio(0)

// ---------------------------------------------------------------------------
// Kernel 1: x fp32 -> bf16
// ---------------------------------------------------------------------------
__global__ __launch_bounds__(256) void convert_x_kernel(
    const float* __restrict__ x, short* __restrict__ xb) {
    int tid = blockIdx.x * blockDim.x + threadIdx.x;
    int stride = gridDim.x * blockDim.x;
    const int n8 = (M_DIM * IN_F) / 8;
    for (int i = tid; i < n8; i += stride) {
        f32x4 a = ((const f32x4*)x)[2 * i];
        f32x4 b = ((const f32x4*)x)[2 * i + 1];
        short8 o;
        o[0] = f2bf(a[0]); o[1] = f2bf(a[1]); o[2] = f2bf(a[2]); o[3] = f2bf(a[3]);
        o[4] = f2bf(b[0]); o[5] = f2bf(b[1]); o[6] = f2bf(b[2]); o[7] = f2bf(b[3]);
        ((short8*)xb)[i] = o;
    }
}

// ---------------------------------------------------------------------------
// Kernel 2: reconstruct w (unchanged from passing round)
// ---------------------------------------------------------------------------
__global__ __launch_bounds__(256) void reconstruct_w_kernel(
    const int* __restrict__ qw, const float* __restrict__ u,
    const float* __restrict__ vt, short* __restrict__ wb) {
    __shared__ float vts[W_BIT][KRANK][128];
    __shared__ float us[W_BIT][KRANK][64];

    const int t = threadIdx.x;
    const int o0 = blockIdx.y * 64;
    const int c0 = blockIdx.x * 128;

    for (int idx = t; idx < W_BIT * KRANK * 128; idx += 256) {
        int i = idx >> 11;
        int rem = idx & 2047;
        int k = rem >> 7;
        int c = rem & 127;
        vts[i][k][c] = vt[(i * KRANK + k) * IN_F + c0 + c];
    }
    for (int idx = t; idx < W_BIT * KRANK * 64; idx += 256) {
        int i = idx >> 10;
        int rem = idx & 1023;
        int o = rem >> 4;
        int k = rem & 15;
        us[i][k][o] = u[((size_t)i * OUT_F + o0 + o) * KRANK + k];
    }
    __syncthreads();

    const int to = (t >> 4) * 4;
    const int tc = (t & 15) * 8;

    float wacc[4][8];
#pragma unroll
    for (int r = 0; r < 4; ++r)
#pragma unroll
        for (int c = 0; c < 8; ++c) wacc[r][c] = 0.f;

#pragma unroll
    for (int i = 0; i < W_BIT; ++i) {
        float dot[4][8];
#pragma unroll
        for (int r = 0; r < 4; ++r)
#pragma unroll
            for (int c = 0; c < 8; ++c) dot[r][c] = 0.f;

#pragma unroll
        for (int k = 0; k < KRANK; ++k) {
            f32x4 uv = *(const f32x4*)&us[i][k][to];
            f32x4 v0 = *(const f32x4*)&vts[i][k][tc];
            f32x4 v1 = *(const f32x4*)&vts[i][k][tc + 4];
#pragma unroll
            for (int r = 0; r < 4; ++r) {
#pragma unroll
                for (int c = 0; c < 4; ++c) {
                    dot[r][c]     += uv[r] * v0[c];
                    dot[r][c + 4] += uv[r] * v1[c];
                }
            }
        }
#pragma unroll
        for (int r = 0; r < 4; ++r) {
            unsigned byte = (unsigned)qw[i * QW_PLANE + (((o0 + to + r) * IN_F + c0 + tc) >> 3)];
#pragma unroll
            for (int c = 0; c < 8; ++c) {
                wacc[r][c] += ((byte >> c) & 1u) ? dot[r][c] : -dot[r][c];
            }
        }
    }

#pragma unroll
    for (int r = 0; r < 4; ++r) {
        short8 o8;
#pragma unroll
        for (int c = 0; c < 8; ++c) o8[c] = f2bf(wacc[r][c]);
        *(short8*)&wb[(size_t)(o0 + to + r) * IN_F + c0 + tc] = o8;
    }
}

// ---------------------------------------------------------------------------
// Kernel 3: C[M,N] = A[M,K] @ B[N,K]^T, 256x256 tile, BK=64, 8 waves (2x4).
// 4 phases/K-tile, 16 MFMA each (m-half x 4n x 1kk). ds_reads issued ONE
// PHASE AHEAD with counted lgkmcnt; staging A(g+1) at P1 / B(g+2) at P4 with
// counted vmcnt(4) once per K-tile. XOR-swizzled LDS (both-sides, linear
// global_load_lds dest). LDS 128 KiB: buf b: A at b*32768, B at +16384.
// ---------------------------------------------------------------------------
__global__ __launch_bounds__(512, 2) void gemm256_kernel(
    const short* __restrict__ A, const short* __restrict__ B, float* __restrict__ C) {
    extern __shared__ short lds[];

    const int t = threadIdx.x;
    const int lane = t & 63, wid = t >> 6;
    const int wr = wid >> 2, wc = wid & 3;       // 2 x 4 wave grid
    const int fr = lane & 15, fq = lane >> 4;

    const int bid = blockIdx.x;
    const int cpx = gridDim.x >> 3;              // grid 1376 % 8 == 0
    const int swz = (bid & 7) * cpx + (bid >> 3);
    const int bm = swz / NBN, bn = swz % NBN;
    const long row0 = (long)bm * 256, col0 = (long)bn * 256;

    // staging: linear LDS dest, inverse-swizzled global source (16B chunks)
    const int srow_b = t >> 3;                                 // 0..63
    const int scol = (((t & 7) ^ ((t >> 3) & 7)) << 3);
    const short* gA = A + (row0 + srow_b) * K_DIM + scol;
    const short* gB = B + (col0 + srow_b) * K_DIM + scol;
    const int ldst = t * 8;

    // fragment read offsets (swizzled col)
    const int arow = (wr * 128 + fr) * 64;
    const int brow = (wc * 64 + fr) * 64;
    const int cswz = (fr & 7) << 3;
    const int colk0  = (fq << 3) ^ cswz;
    const int colk32 = (32 | (fq << 3)) ^ cswz;

    f32x4 acc[8][4];
#pragma unroll
    for (int m = 0; m < 8; ++m)
#pragma unroll
        for (int n = 0; n < 4; ++n) acc[m][n] = (f32x4)0.f;

    // af[j]: j=0 kk0/m0-3, 1 kk0/m4-7, 2 kk32/m0-3, 3 kk32/m4-7. bf[j]: kk0,kk32
    short8 af[4][4], bf[2][4];

#define STAGE4(gp, base, ktcol)                                        \
    _Pragma("unroll") for (int l = 0; l < 4; ++l)                      \
        async16(&lds[(base) + ldst + l * 4096],                        \
                (gp) + (size_t)l * 64 * K_DIM + (ktcol))

#define LDA4(j, base, mh, colk)                                        \
    _Pragma("unroll") for (int m = 0; m < 4; ++m)                      \
        af[j][m] = *(const short8*)&lds[(base) + arow + (mh) * 4096 + m * 1024 + (colk)]

#define LDB4(j, base, colk)                                            \
    _Pragma("unroll") for (int n = 0; n < 4; ++n)                      \
        bf[j][n] = *(const short8*)&lds[(base) + 16384 + brow + n * 1024 + (colk)]

#define MFQ(j, jb, mbase)                                              \
    _Pragma("unroll") for (int m = 0; m < 4; ++m)                      \
        _Pragma("unroll") for (int n = 0; n < 4; ++n)                  \
            acc[(mbase) + m][n] = __builtin_amdgcn_mfma_f32_16x16x32_bf16( \
                af[j][m], bf[jb][n], acc[(mbase) + m][n], 0, 0, 0)

    // ---- prologue: tile0 -> buf0 (8), B(1) -> buf1 (4)
    STAGE4(gA, 0, 0);
    STAGE4(gB, 16384, 0);
    STAGE4(gB, 32768 + 16384, 64);
    VMC(4);            // tile0's 8 landed (B(1)'s 4 still in flight)
    BAR();
    LDA4(0, 0, 0, colk0);   // af[0]: kk0 m0-3
    LDB4(0, 0, colk0);      // bf[0]: kk0

    for (int g = 0; g < NT; ++g) {
        const int cur = (g & 1) * 32768;
        const int oth = 32768 - cur;
        const bool h1 = (g + 1 < NT);
        const bool h2 = (g + 2 < NT);

        // ---- P1: MFMA af[0] x bf[0]; issue af[1]; stage A(g+1) -> A[oth]
        if (h1) STAGE4(gA, oth, (size_t)(g + 1) * 64);
        LDA4(1, cur, 1, colk0);
        BAR();
        LGKM(4);           // af[0], bf[0] resident (issued last phase)
        PRIO1(); MFQ(0, 0, 0); PRIO0();
        SBAR0();
        BAR();

        // ---- P2: MFMA af[1] x bf[0]; issue af[2] + bf[1]
        LDA4(2, cur, 0, colk32);
        LDB4(1, cur, colk32);
        BAR();
        LGKM(8);           // af[1] resident
        PRIO1(); MFQ(1, 0, 4); PRIO0();
        SBAR0();
        BAR();

        // ---- P3: MFMA af[2] x bf[1]; issue af[3]
        LDA4(3, cur, 1, colk32);
        BAR();
        LGKM(4);           // af[2], bf[1] resident
        PRIO1(); MFQ(2, 1, 0); PRIO0();
        SBAR0();
        BAR();

        // ---- P4: MFMA af[3] x bf[1]; stage B(g+2) -> B[cur]; vmcnt gate;
        //          issue next tile's af[0], bf[0] from oth
        if (h2) STAGE4(gB, cur + 16384, (size_t)(g + 2) * 64);
        if (h2) { VMC(4); } else { VMC(0); }   // tile g+1 fully landed
        BAR();
        if (h1) {
            LDA4(0, oth, 0, colk0);
            LDB4(0, oth, colk0);
            LGKM(8);       // af[3] resident
        } else {
            LGKM(0);
        }
        PRIO1(); MFQ(3, 1, 4); PRIO0();
        SBAR0();
        BAR();
    }

    // ---- epilogue: C/D layout col = lane&15, row = (lane>>4)*4 + j
#pragma unroll
    for (int m = 0; m < 8; ++m) {
#pragma unroll
        for (int n = 0; n < 4; ++n) {
            f32x4 v = acc[m][n];
            long r0 = row0 + wr * 128 + m * 16 + fq * 4;
            long cc = col0 + wc * 64 + n * 16 + fr;
#pragma unroll
            for (int jj = 0; jj < 4; ++jj)
                C[(size_t)(r0 + jj) * N_DIM + cc] = v[jj];
        }
    }
#undef STAGE4
#undef LDA4
#undef LDB4
#undef MFQ
}

// ---------------------------------------------------------------------------
extern "C" void kernel_launch(void* const* d_in, const int* in_sizes, int n_in,
                              void* d_out, int out_size, void* d_ws, size_t ws_size,
                              hipStream_t stream) {
    const float* x  = (const float*)d_in[0];
    const int*   qw = (const int*)d_in[1];
    const float* u  = (const float*)d_in[2];
    const float* vt = (const float*)d_in[3];
    float* out = (float*)d_out;

    const size_t wb_bytes = (size_t)OUT_F * IN_F * 2;
    short* wb = (short*)d_ws;
    short* xb = (short*)((char*)d_ws + wb_bytes);

    (void)hipFuncSetAttribute((const void*)gemm256_kernel,
                              hipFuncAttributeMaxDynamicSharedMemorySize, 131072);

    hipLaunchKernelGGL(convert_x_kernel, dim3(2048), dim3(256), 0, stream, x, xb);
    hipLaunchKernelGGL(reconstruct_w_kernel, dim3(IN_F / 128, OUT_F / 64), dim3(256), 0, stream,
                       qw, u, vt, wb);
    hipLaunchKernelGGL(gemm256_kernel, dim3((M_DIM / 256) * (N_DIM / 256)), dim3(512), 131072,
                       stream, xb, wb, out);
}